// Round 1
// baseline (133.753 us; speedup 1.0000x reference)
//
#include <hip/hip_runtime.h>

#define BSZ   4
#define NG    15135
#define MROWS (BSZ*NG)     // 60540
#define NF    64
#define H     128
#define NCMT  1000
#define NEDGE 100000
#define HFC   256
#define NCLS  10

// ---------------------------------------------------------------------------
// K0: init accumulators in workspace
// ---------------------------------------------------------------------------
__global__ __launch_bounds__(256) void k0_init(float* __restrict__ acc,
                                               int* __restrict__ cnt,
                                               float* __restrict__ hacc,
                                               const float* __restrict__ bl1) {
    int t = blockIdx.x * 256 + threadIdx.x;
    if (t < BSZ * NCMT) acc[t] = 0.f;
    if (t < NCMT)       cnt[t] = 0;
    if (t < BSZ * HFC)  hacc[t] = bl1[t & (HFC - 1)];
}

// ---------------------------------------------------------------------------
// K1: fused  h1 = relu(x@W1+b1); h2 = relu(h1@W2+b2);
//            fdot[r] = sum_k h1[k]*Wfc[2k] + h2[k]*Wfc[2k+1]
// 64 rows per block, 512 threads = 8 waves; wave w owns rows 8w..8w+7.
// Lane owns 2 output columns (j0 = 2*lane). W1/W2 staged in LDS; per-wave
// private h1 stash (no inter-phase barrier). LDS = 128 KiB exactly.
// ---------------------------------------------------------------------------
__global__ __launch_bounds__(512, 1) void k1_fdot(const float* __restrict__ x,
                                                  const float* __restrict__ W1,
                                                  const float* __restrict__ b1,
                                                  const float* __restrict__ W2,
                                                  const float* __restrict__ b2,
                                                  const float* __restrict__ Wfc,
                                                  float* __restrict__ fdot) {
    __shared__ float w1s[NF * H];       // 32 KB
    __shared__ float w2s[H * H];        // 64 KB
    __shared__ float h1p[8][H][8];      // 32 KB : [wave][j][row_i]

    const int tid = threadIdx.x;

    // stage weights (coalesced float4)
    {
        const float4* s1 = (const float4*)W1; float4* d1 = (float4*)w1s;
        #pragma unroll
        for (int i = 0; i < (NF * H / 4) / 512; ++i) d1[i * 512 + tid] = s1[i * 512 + tid];
        const float4* s2 = (const float4*)W2; float4* d2 = (float4*)w2s;
        #pragma unroll
        for (int i = 0; i < (H * H / 4) / 512; ++i) d2[i * 512 + tid] = s2[i * 512 + tid];
    }
    __syncthreads();

    const int lane = tid & 63;
    const int wid  = tid >> 6;
    const int j0   = lane * 2;
    const int tile0 = blockIdx.x * 64;
    // wave-uniform row base -> scalar loads for x
    const int rbase = __builtin_amdgcn_readfirstlane(tile0 + wid * 8);

    const float* xp[8];
    #pragma unroll
    for (int i = 0; i < 8; ++i) {
        int r = rbase + i; if (r > MROWS - 1) r = MROWS - 1;   // clamp (results unused)
        xp[i] = x + (size_t)r * NF;
    }

    // ---- phase 1: h1 = relu(x @ W1 + b1) ----
    float acc[8][2];
    #pragma unroll
    for (int i = 0; i < 8; ++i) { acc[i][0] = 0.f; acc[i][1] = 0.f; }

    #pragma unroll 4
    for (int f = 0; f < NF; ++f) {
        const float2 wv = *(const float2*)&w1s[f * H + j0];
        #pragma unroll
        for (int i = 0; i < 8; ++i) {
            const float xv = xp[i][f];
            acc[i][0] = fmaf(xv, wv.x, acc[i][0]);
            acc[i][1] = fmaf(xv, wv.y, acc[i][1]);
        }
    }

    const float bb0 = b1[j0],        bb1 = b1[j0 + 1];
    const float we0 = Wfc[2 * j0],   we1 = Wfc[2 * j0 + 2];   // even slots (h1)
    const float wo0 = Wfc[2 * j0 + 1], wo1 = Wfc[2 * j0 + 3]; // odd slots (h2)

    float fp[8], hv0[8], hv1[8];
    #pragma unroll
    for (int i = 0; i < 8; ++i) {
        hv0[i] = fmaxf(acc[i][0] + bb0, 0.f);
        hv1[i] = fmaxf(acc[i][1] + bb1, 0.f);
        fp[i]  = fmaf(hv0[i], we0, hv1[i] * we1);
    }
    // stash h1 (per-wave private; consumed by same wave only)
    *(float4*)&h1p[wid][j0][0]     = make_float4(hv0[0], hv0[1], hv0[2], hv0[3]);
    *(float4*)&h1p[wid][j0][4]     = make_float4(hv0[4], hv0[5], hv0[6], hv0[7]);
    *(float4*)&h1p[wid][j0 + 1][0] = make_float4(hv1[0], hv1[1], hv1[2], hv1[3]);
    *(float4*)&h1p[wid][j0 + 1][4] = make_float4(hv1[4], hv1[5], hv1[6], hv1[7]);

    // ---- phase 2: h2 = relu(h1 @ W2 + b2), accumulate fdot ----
    float ac2[8][2];
    #pragma unroll
    for (int i = 0; i < 8; ++i) { ac2[i][0] = 0.f; ac2[i][1] = 0.f; }

    #pragma unroll 2
    for (int f = 0; f < H; ++f) {
        const float4 ha = *(const float4*)&h1p[wid][f][0];   // broadcast read
        const float4 hb = *(const float4*)&h1p[wid][f][4];
        const float2 wv = *(const float2*)&w2s[f * H + j0];
        ac2[0][0] = fmaf(ha.x, wv.x, ac2[0][0]); ac2[0][1] = fmaf(ha.x, wv.y, ac2[0][1]);
        ac2[1][0] = fmaf(ha.y, wv.x, ac2[1][0]); ac2[1][1] = fmaf(ha.y, wv.y, ac2[1][1]);
        ac2[2][0] = fmaf(ha.z, wv.x, ac2[2][0]); ac2[2][1] = fmaf(ha.z, wv.y, ac2[2][1]);
        ac2[3][0] = fmaf(ha.w, wv.x, ac2[3][0]); ac2[3][1] = fmaf(ha.w, wv.y, ac2[3][1]);
        ac2[4][0] = fmaf(hb.x, wv.x, ac2[4][0]); ac2[4][1] = fmaf(hb.x, wv.y, ac2[4][1]);
        ac2[5][0] = fmaf(hb.y, wv.x, ac2[5][0]); ac2[5][1] = fmaf(hb.y, wv.y, ac2[5][1]);
        ac2[6][0] = fmaf(hb.z, wv.x, ac2[6][0]); ac2[6][1] = fmaf(hb.z, wv.y, ac2[6][1]);
        ac2[7][0] = fmaf(hb.w, wv.x, ac2[7][0]); ac2[7][1] = fmaf(hb.w, wv.y, ac2[7][1]);
    }

    const float cb0 = b2[j0], cb1 = b2[j0 + 1];
    #pragma unroll
    for (int i = 0; i < 8; ++i) {
        const float h2a = fmaxf(ac2[i][0] + cb0, 0.f);
        const float h2b = fmaxf(ac2[i][1] + cb1, 0.f);
        fp[i] = fmaf(h2a, wo0, fp[i]);
        fp[i] = fmaf(h2b, wo1, fp[i]);
    }

    // wave-reduce fp[i] over 64 lanes (each lane holds 2 cols' contribution)
    #pragma unroll
    for (int i = 0; i < 8; ++i) {
        float v = fp[i];
        #pragma unroll
        for (int off = 32; off > 0; off >>= 1) v += __shfl_xor(v, off, 64);
        if (lane == 0) {
            const int r = rbase + i;
            if (r < MROWS) fdot[r] = v;
        }
    }
}

// ---------------------------------------------------------------------------
// K2: edge scatter  acc[b][c] += fdot[b][row[e]] ; cnt[c] += 1
// ---------------------------------------------------------------------------
__global__ __launch_bounds__(256) void k2_scatter(const int* __restrict__ row,
                                                  const int* __restrict__ col,
                                                  const float* __restrict__ fdot,
                                                  float* __restrict__ acc,
                                                  int* __restrict__ cnt) {
    int e = blockIdx.x * 256 + threadIdx.x;
    if (e >= NEDGE) return;
    const int r = row[e];
    const int c = col[e];
    atomicAdd(&cnt[c], 1);
    #pragma unroll
    for (int b = 0; b < BSZ; ++b)
        atomicAdd(&acc[b * NCMT + c], fdot[b * NG + r]);
}

// ---------------------------------------------------------------------------
// K3a: hacc[b][j] += sum_{c in chunk} scores[b][c] * Wl1[c][j]
//      scores[b][c] = acc[b][c]/max(cnt[c],1) + bfc
// ---------------------------------------------------------------------------
#define CCH 25
__global__ __launch_bounds__(256) void k3a_head1(const float* __restrict__ acc,
                                                 const int* __restrict__ cnt,
                                                 const float* __restrict__ bfc,
                                                 const float* __restrict__ Wl1,
                                                 float* __restrict__ hacc) {
    __shared__ float sc[BSZ][CCH];
    const int c0 = blockIdx.x * CCH;
    const int t = threadIdx.x;
    if (t < BSZ * CCH) {
        const int b = t / CCH, cc = t % CCH;
        const int c = c0 + cc;
        const int n = cnt[c];
        sc[b][cc] = acc[b * NCMT + c] / (float)(n > 0 ? n : 1) + bfc[0];
    }
    __syncthreads();
    float p0 = 0.f, p1 = 0.f, p2 = 0.f, p3 = 0.f;
    #pragma unroll
    for (int cc = 0; cc < CCH; ++cc) {
        const float wv = Wl1[(size_t)(c0 + cc) * HFC + t];
        p0 = fmaf(sc[0][cc], wv, p0);
        p1 = fmaf(sc[1][cc], wv, p1);
        p2 = fmaf(sc[2][cc], wv, p2);
        p3 = fmaf(sc[3][cc], wv, p3);
    }
    atomicAdd(&hacc[0 * HFC + t], p0);
    atomicAdd(&hacc[1 * HFC + t], p1);
    atomicAdd(&hacc[2 * HFC + t], p2);
    atomicAdd(&hacc[3 * HFC + t], p3);
}

// ---------------------------------------------------------------------------
// K3b: logits = relu(hacc) @ Wl2 + bl2 ; out = log_softmax(logits)
// ---------------------------------------------------------------------------
__global__ __launch_bounds__(64) void k3b_head2(const float* __restrict__ hacc,
                                                const float* __restrict__ Wl2,
                                                const float* __restrict__ bl2,
                                                float* __restrict__ out) {
    __shared__ float lg[BSZ][NCLS];
    const int t = threadIdx.x;
    if (t < BSZ * NCLS) {
        const int b = t / NCLS, k = t % NCLS;
        float a = bl2[k];
        for (int j = 0; j < HFC; ++j)
            a = fmaf(fmaxf(hacc[b * HFC + j], 0.f), Wl2[j * NCLS + k], a);
        lg[b][k] = a;
    }
    __syncthreads();
    if (t < BSZ * NCLS) {
        const int b = t / NCLS, k = t % NCLS;
        float m = lg[b][0];
        #pragma unroll
        for (int k2 = 1; k2 < NCLS; ++k2) m = fmaxf(m, lg[b][k2]);
        float s = 0.f;
        #pragma unroll
        for (int k2 = 0; k2 < NCLS; ++k2) s += expf(lg[b][k2] - m);
        out[b * NCLS + k] = lg[b][k] - m - logf(s);
    }
}

// ---------------------------------------------------------------------------
extern "C" void kernel_launch(void* const* d_in, const int* in_sizes, int n_in,
                              void* d_out, int out_size, void* d_ws, size_t ws_size,
                              hipStream_t stream) {
    const float* x   = (const float*)d_in[0];
    // d_in[1] = batch (unused)
    const int*   row = (const int*)d_in[2];
    const int*   col = (const int*)d_in[3];
    const float* W1  = (const float*)d_in[4];
    const float* b1  = (const float*)d_in[5];
    const float* W2  = (const float*)d_in[6];
    const float* b2  = (const float*)d_in[7];
    const float* Wfc = (const float*)d_in[8];
    const float* bfc = (const float*)d_in[9];
    const float* Wl1 = (const float*)d_in[10];
    const float* bl1 = (const float*)d_in[11];
    const float* Wl2 = (const float*)d_in[12];
    const float* bl2 = (const float*)d_in[13];

    float* ws   = (float*)d_ws;
    float* fdot = ws;                    // 60544 floats
    float* acc  = ws + 60544;            // 4000
    int*   cnt  = (int*)(ws + 64544);    // 1000
    float* hacc = ws + 65544;            // 1024

    k0_init<<<16, 256, 0, stream>>>(acc, cnt, hacc, bl1);
    k1_fdot<<<(MROWS + 63) / 64, 512, 0, stream>>>(x, W1, b1, W2, b2, Wfc, fdot);
    k2_scatter<<<(NEDGE + 255) / 256, 256, 0, stream>>>(row, col, fdot, acc, cnt);
    k3a_head1<<<NCMT / CCH, 256, 0, stream>>>(acc, cnt, bfc, Wl1, hacc);
    k3b_head2<<<1, 64, 0, stream>>>(hacc, Wl2, bl2, (float*)d_out);
}

// Round 2
// 79.770 us; speedup vs baseline: 1.6767x; 1.6767x over previous
//
#include <hip/hip_runtime.h>

#define BSZ   4
#define NG    15135
#define MROWS (BSZ*NG)     // 60540
#define NF    64
#define H     128
#define NCMT  1000
#define NEDGE 100000
#define HFC   256
#define NCLS  10

typedef __attribute__((ext_vector_type(8))) short  bfrag;   // 8 bf16 = 4 VGPR
typedef __attribute__((ext_vector_type(4))) float  f32x4;

__device__ __forceinline__ unsigned short f2bf(float f) {
    union { float f; unsigned int u; } v; v.f = f;
    unsigned int u = v.u;
    return (unsigned short)((u + 0x7FFFu + ((u >> 16) & 1u)) >> 16);  // RNE
}

// ---------------------------------------------------------------------------
// kP: pack W1^T / W2^T into MFMA-A fragment-linear bf16 layout in ws, and
//     init the accumulators.  48 blocks x 256 thr; thread q packs ushorts
//     2q,2q+1 of the concatenated [w1frag(8192) | w2frag(16384)] buffer.
// frag layout: elem ((ci*NT + t)*64 + l)*8 + kk  =  W[t*32+(l>>4)*8+kk][ci*16+(l&15)]
// ---------------------------------------------------------------------------
__global__ __launch_bounds__(256) void kP(const float* __restrict__ W1,
                                          const float* __restrict__ W2,
                                          const float* __restrict__ bl1,
                                          unsigned int* __restrict__ wfrag_u32,
                                          float* __restrict__ acc,
                                          int* __restrict__ cnt,
                                          float* __restrict__ hacc) {
    const int q = blockIdx.x * 256 + threadIdx.x;   // 0..12287
    if (q < BSZ * NCMT) acc[q] = 0.f;
    if (q < NCMT)       cnt[q] = 0;
    if (q < BSZ * HFC)  hacc[q] = bl1[q & (HFC - 1)];

    const int e = 2 * q;
    float f0, f1;
    if (e < 8192) {                       // W1 frags: ct = ci*2+t (16)
        const int kk = e & 7, l = (e >> 3) & 63, ct = e >> 9;
        const int t = ct & 1, ci = ct >> 1;
        const int k = t * 32 + (l >> 4) * 8 + kk;
        const int i = ci * 16 + (l & 15);
        f0 = W1[k * H + i];
        f1 = W1[(k + 1) * H + i];
    } else {                              // W2 frags: ct = ci*4+t (32)
        const int e2 = e - 8192;
        const int kk = e2 & 7, l = (e2 >> 3) & 63, ct = e2 >> 9;
        const int t = ct & 3, ci = ct >> 2;
        const int k = t * 32 + (l >> 4) * 8 + kk;
        const int i = ci * 16 + (l & 15);
        f0 = W2[k * H + i];
        f1 = W2[(k + 1) * H + i];
    }
    wfrag_u32[q] = (unsigned int)f2bf(f0) | ((unsigned int)f2bf(f1) << 16);
}

// ---------------------------------------------------------------------------
// K1: bf16-MFMA fused  h1 = relu(x@W1+b1); h2 = relu(h1@W2+b2);
//     fdot[r] = sum_c h1[c]*Wfc[2c] + h2[c]*Wfc[2c+1]
// Swapped operands: C[channel][row].  4 waves x 16 rows = 64 rows/block.
// LDS 65KB -> 2 blocks/CU.  h1 stash is wave-private: no barriers in main loop.
// ---------------------------------------------------------------------------
__global__ __launch_bounds__(256, 2) void k1_fdot(const float* __restrict__ x,
                                                  const unsigned int* __restrict__ wfrag_g,
                                                  const float* __restrict__ b1,
                                                  const float* __restrict__ b2,
                                                  const float* __restrict__ Wfc,
                                                  float* __restrict__ fdot) {
    __shared__ unsigned int   wfrag[12288];        // 48KB: w1 [0,4096) w2 [4096,12288)
    __shared__ unsigned short h1s[4][16][136];     // 17408B, pad 128->136 (bank-balanced)

    const int tid = threadIdx.x;
    {   // stage fragment weights: straight linear copy (conflict-free)
        const uint4* src = (const uint4*)wfrag_g;
        uint4* dst = (uint4*)wfrag;
        #pragma unroll
        for (int i = 0; i < 12; ++i) dst[i * 256 + tid] = src[i * 256 + tid];
    }
    __syncthreads();

    const int lane = tid & 63, wid = tid >> 6;
    const int sub = lane & 15, grp = lane >> 4;
    const int r  = blockIdx.x * 64 + wid * 16 + sub;
    const int rc = r < MROWS ? r : MROWS - 1;

    // B-fragments of GEMM1: x row (8 contiguous floats/lane -> bf16x8)
    bfrag bx[2];
    #pragma unroll
    for (int t = 0; t < 2; ++t) {
        const float4 xa = *(const float4*)&x[(size_t)rc * NF + t * 32 + grp * 8];
        const float4 xb = *(const float4*)&x[(size_t)rc * NF + t * 32 + grp * 8 + 4];
        union { bfrag v; unsigned int u[4]; } pk;
        pk.u[0] = (unsigned int)f2bf(xa.x) | ((unsigned int)f2bf(xa.y) << 16);
        pk.u[1] = (unsigned int)f2bf(xa.z) | ((unsigned int)f2bf(xa.w) << 16);
        pk.u[2] = (unsigned int)f2bf(xb.x) | ((unsigned int)f2bf(xb.y) << 16);
        pk.u[3] = (unsigned int)f2bf(xb.z) | ((unsigned int)f2bf(xb.w) << 16);
        bx[t] = pk.v;
    }

    const bfrag* w1f = (const bfrag*)wfrag;                 // [(ci*2+t)*64 + lane]
    const bfrag* w2f = (const bfrag*)(wfrag + 4096);        // [(ci*4+t)*64 + lane]
    float fp = 0.f;

    // ---- GEMM1: C1[channel][row], 8 channel-tiles x K=64 ----
    #pragma unroll
    for (int ci = 0; ci < 8; ++ci) {
        f32x4 c1 = {0.f, 0.f, 0.f, 0.f};
        c1 = __builtin_amdgcn_mfma_f32_16x16x32_bf16(w1f[(ci * 2 + 0) * 64 + lane], bx[0], c1, 0, 0, 0);
        c1 = __builtin_amdgcn_mfma_f32_16x16x32_bf16(w1f[(ci * 2 + 1) * 64 + lane], bx[1], c1, 0, 0, 0);
        const int c0 = ci * 16 + grp * 4;                   // channel base (4 contiguous)
        const float4 b1v = *(const float4*)&b1[c0];
        const float4 wfa = *(const float4*)&Wfc[2 * c0];        // we(c0),wo(c0),we(c0+1),wo(c0+1)
        const float4 wfb = *(const float4*)&Wfc[2 * c0 + 4];
        const float h0 = fmaxf(c1[0] + b1v.x, 0.f);
        const float h1 = fmaxf(c1[1] + b1v.y, 0.f);
        const float h2 = fmaxf(c1[2] + b1v.z, 0.f);
        const float h3 = fmaxf(c1[3] + b1v.w, 0.f);
        fp = fmaf(h0, wfa.x, fp); fp = fmaf(h1, wfa.z, fp);
        fp = fmaf(h2, wfb.x, fp); fp = fmaf(h3, wfb.z, fp);
        const unsigned int lo = (unsigned int)f2bf(h0) | ((unsigned int)f2bf(h1) << 16);
        const unsigned int hi = (unsigned int)f2bf(h2) | ((unsigned int)f2bf(h3) << 16);
        *(uint2*)&h1s[wid][sub][c0] = make_uint2(lo, hi);   // wave-private stash
    }

    // ---- GEMM2: B = h1^T from stash (b128, bank-balanced), K=128 ----
    bfrag bh[4];
    #pragma unroll
    for (int t = 0; t < 4; ++t)
        bh[t] = *(const bfrag*)&h1s[wid][sub][t * 32 + grp * 8];

    #pragma unroll
    for (int ci = 0; ci < 8; ++ci) {
        f32x4 c2 = {0.f, 0.f, 0.f, 0.f};
        #pragma unroll
        for (int t = 0; t < 4; ++t)
            c2 = __builtin_amdgcn_mfma_f32_16x16x32_bf16(w2f[(ci * 4 + t) * 64 + lane], bh[t], c2, 0, 0, 0);
        const int c0 = ci * 16 + grp * 4;
        const float4 b2v = *(const float4*)&b2[c0];
        const float4 wfa = *(const float4*)&Wfc[2 * c0];
        const float4 wfb = *(const float4*)&Wfc[2 * c0 + 4];
        fp = fmaf(fmaxf(c2[0] + b2v.x, 0.f), wfa.y, fp);
        fp = fmaf(fmaxf(c2[1] + b2v.y, 0.f), wfa.w, fp);
        fp = fmaf(fmaxf(c2[2] + b2v.z, 0.f), wfb.y, fp);
        fp = fmaf(fmaxf(c2[3] + b2v.w, 0.f), wfb.w, fp);
    }

    // reduce over channel groups (lane bits 4,5); row = sub
    fp += __shfl_xor(fp, 16);
    fp += __shfl_xor(fp, 32);
    if (grp == 0 && r < MROWS) fdot[r] = fp;
}

// ---------------------------------------------------------------------------
// K2: edge scatter  acc[b][c] += fdot[b][row[e]] ; cnt[c] += 1
// ---------------------------------------------------------------------------
__global__ __launch_bounds__(256) void k2_scatter(const int* __restrict__ row,
                                                  const int* __restrict__ col,
                                                  const float* __restrict__ fdot,
                                                  float* __restrict__ acc,
                                                  int* __restrict__ cnt) {
    int e = blockIdx.x * 256 + threadIdx.x;
    if (e >= NEDGE) return;
    const int r = row[e];
    const int c = col[e];
    atomicAdd(&cnt[c], 1);
    #pragma unroll
    for (int b = 0; b < BSZ; ++b)
        atomicAdd(&acc[b * NCMT + c], fdot[b * NG + r]);
}

// ---------------------------------------------------------------------------
// K3a: hacc[b][j] += sum_{c in chunk} scores[b][c] * Wl1[c][j]
// ---------------------------------------------------------------------------
#define CCH 25
__global__ __launch_bounds__(256) void k3a_head1(const float* __restrict__ acc,
                                                 const int* __restrict__ cnt,
                                                 const float* __restrict__ bfc,
                                                 const float* __restrict__ Wl1,
                                                 float* __restrict__ hacc) {
    __shared__ float sc[BSZ][CCH];
    const int c0 = blockIdx.x * CCH;
    const int t = threadIdx.x;
    if (t < BSZ * CCH) {
        const int b = t / CCH, cc = t % CCH;
        const int c = c0 + cc;
        const int n = cnt[c];
        sc[b][cc] = acc[b * NCMT + c] / (float)(n > 0 ? n : 1) + bfc[0];
    }
    __syncthreads();
    float p0 = 0.f, p1 = 0.f, p2 = 0.f, p3 = 0.f;
    #pragma unroll
    for (int cc = 0; cc < CCH; ++cc) {
        const float wv = Wl1[(size_t)(c0 + cc) * HFC + t];
        p0 = fmaf(sc[0][cc], wv, p0);
        p1 = fmaf(sc[1][cc], wv, p1);
        p2 = fmaf(sc[2][cc], wv, p2);
        p3 = fmaf(sc[3][cc], wv, p3);
    }
    atomicAdd(&hacc[0 * HFC + t], p0);
    atomicAdd(&hacc[1 * HFC + t], p1);
    atomicAdd(&hacc[2 * HFC + t], p2);
    atomicAdd(&hacc[3 * HFC + t], p3);
}

// ---------------------------------------------------------------------------
// K3b: logits = relu(hacc) @ Wl2 + bl2 ; out = log_softmax(logits)
// ---------------------------------------------------------------------------
__global__ __launch_bounds__(64) void k3b_head2(const float* __restrict__ hacc,
                                                const float* __restrict__ Wl2,
                                                const float* __restrict__ bl2,
                                                float* __restrict__ out) {
    __shared__ float lg[BSZ][NCLS];
    const int t = threadIdx.x;
    if (t < BSZ * NCLS) {
        const int b = t / NCLS, k = t % NCLS;
        float a = bl2[k];
        for (int j = 0; j < HFC; ++j)
            a = fmaf(fmaxf(hacc[b * HFC + j], 0.f), Wl2[j * NCLS + k], a);
        lg[b][k] = a;
    }
    __syncthreads();
    if (t < BSZ * NCLS) {
        const int b = t / NCLS, k = t % NCLS;
        float m = lg[b][0];
        #pragma unroll
        for (int k2 = 1; k2 < NCLS; ++k2) m = fmaxf(m, lg[b][k2]);
        float s = 0.f;
        #pragma unroll
        for (int k2 = 0; k2 < NCLS; ++k2) s += expf(lg[b][k2] - m);
        out[b * NCLS + k] = lg[b][k] - m - logf(s);
    }
}

// ---------------------------------------------------------------------------
extern "C" void kernel_launch(void* const* d_in, const int* in_sizes, int n_in,
                              void* d_out, int out_size, void* d_ws, size_t ws_size,
                              hipStream_t stream) {
    const float* x   = (const float*)d_in[0];
    // d_in[1] = batch (unused)
    const int*   row = (const int*)d_in[2];
    const int*   col = (const int*)d_in[3];
    const float* W1  = (const float*)d_in[4];
    const float* b1  = (const float*)d_in[5];
    const float* W2  = (const float*)d_in[6];
    const float* b2  = (const float*)d_in[7];
    const float* Wfc = (const float*)d_in[8];
    const float* bfc = (const float*)d_in[9];
    const float* Wl1 = (const float*)d_in[10];
    const float* bl1 = (const float*)d_in[11];
    const float* Wl2 = (const float*)d_in[12];
    const float* bl2 = (const float*)d_in[13];

    float* ws   = (float*)d_ws;
    float* fdot = ws;                          // 60544 floats
    float* acc  = ws + 60544;                  // 4000
    int*   cnt  = (int*)(ws + 64544);          // 1000
    float* hacc = ws + 65544;                  // 1024
    unsigned int* wfrag = (unsigned int*)(ws + 66568);   // 12288 u32 (48KB)

    kP<<<48, 256, 0, stream>>>(W1, W2, bl1, wfrag, acc, cnt, hacc);
    k1_fdot<<<(MROWS + 63) / 64, 256, 0, stream>>>(x, wfrag, b1, b2, Wfc, fdot);
    k2_scatter<<<(NEDGE + 255) / 256, 256, 0, stream>>>(row, col, fdot, acc, cnt);
    k3a_head1<<<NCMT / CCH, 256, 0, stream>>>(acc, cnt, bfc, Wl1, hacc);
    k3b_head2<<<1, 64, 0, stream>>>(hacc, Wl2, bl2, (float*)d_out);
}

// Round 3
// 46.447 us; speedup vs baseline: 2.8797x; 1.7175x over previous
//
#include <hip/hip_runtime.h>

#define BSZ   4
#define NG    15135
#define MROWS (BSZ*NG)     // 60540
#define NF    64
#define H     128
#define NCMT  1000
#define NEDGE 100000
#define HFC   256
#define NCLS  10
#define NB    64           // k2 privatized blocks
#define PSTR  5120         // partial stride (floats): [4*1000 acc | 1000 cnt | pad]

typedef __attribute__((ext_vector_type(8))) short  bfrag;   // 8 bf16 = 4 VGPR
typedef __attribute__((ext_vector_type(4))) float  f32x4;

__device__ __forceinline__ unsigned short f2bf(float f) {
    union { float f; unsigned int u; } v; v.f = f;
    unsigned int u = v.u;
    return (unsigned short)((u + 0x7FFFu + ((u >> 16) & 1u)) >> 16);  // RNE
}

// ---------------------------------------------------------------------------
// kP: pack W1^T / W2^T into MFMA-A fragment-linear bf16 layout in ws, and
//     init hacc with bl1.
// frag layout: elem ((ci*NT + t)*64 + l)*8 + kk  =  W[t*32+(l>>4)*8+kk][ci*16+(l&15)]
// ---------------------------------------------------------------------------
__global__ __launch_bounds__(256) void kP(const float* __restrict__ W1,
                                          const float* __restrict__ W2,
                                          const float* __restrict__ bl1,
                                          unsigned int* __restrict__ wfrag_u32,
                                          float* __restrict__ hacc) {
    const int q = blockIdx.x * 256 + threadIdx.x;   // 0..12287
    if (q < BSZ * HFC) hacc[q] = bl1[q & (HFC - 1)];

    const int e = 2 * q;
    float f0, f1;
    if (e < 8192) {                       // W1 frags: ct = ci*2+t (16)
        const int kk = e & 7, l = (e >> 3) & 63, ct = e >> 9;
        const int t = ct & 1, ci = ct >> 1;
        const int k = t * 32 + (l >> 4) * 8 + kk;
        const int i = ci * 16 + (l & 15);
        f0 = W1[k * H + i];
        f1 = W1[(k + 1) * H + i];
    } else {                              // W2 frags: ct = ci*4+t (32)
        const int e2 = e - 8192;
        const int kk = e2 & 7, l = (e2 >> 3) & 63, ct = e2 >> 9;
        const int t = ct & 3, ci = ct >> 2;
        const int k = t * 32 + (l >> 4) * 8 + kk;
        const int i = ci * 16 + (l & 15);
        f0 = W2[k * H + i];
        f1 = W2[(k + 1) * H + i];
    }
    wfrag_u32[q] = (unsigned int)f2bf(f0) | ((unsigned int)f2bf(f1) << 16);
}

// ---------------------------------------------------------------------------
// K1: bf16-MFMA fused  h1 = relu(x@W1+b1); h2 = relu(h1@W2+b2);
//     fdot4[g][b] = sum_c h1[c]*Wfc[2c] + h2[c]*Wfc[2c+1]   (transposed store)
// Swapped operands: C[channel][row].  4 waves x 16 rows = 64 rows/block.
// ---------------------------------------------------------------------------
__global__ __launch_bounds__(256, 2) void k1_fdot(const float* __restrict__ x,
                                                  const unsigned int* __restrict__ wfrag_g,
                                                  const float* __restrict__ b1,
                                                  const float* __restrict__ b2,
                                                  const float* __restrict__ Wfc,
                                                  float* __restrict__ fdot4) {
    __shared__ unsigned int   wfrag[12288];        // 48KB: w1 [0,4096) w2 [4096,12288)
    __shared__ unsigned short h1s[4][16][136];     // pad 128->136 (bank-balanced)

    const int tid = threadIdx.x;
    {   // stage fragment weights: straight linear copy (conflict-free)
        const uint4* src = (const uint4*)wfrag_g;
        uint4* dst = (uint4*)wfrag;
        #pragma unroll
        for (int i = 0; i < 12; ++i) dst[i * 256 + tid] = src[i * 256 + tid];
    }
    __syncthreads();

    const int lane = tid & 63, wid = tid >> 6;
    const int sub = lane & 15, grp = lane >> 4;
    const int r  = blockIdx.x * 64 + wid * 16 + sub;
    const int rc = r < MROWS ? r : MROWS - 1;

    // B-fragments of GEMM1: x row (8 contiguous floats/lane -> bf16x8)
    bfrag bx[2];
    #pragma unroll
    for (int t = 0; t < 2; ++t) {
        const float4 xa = *(const float4*)&x[(size_t)rc * NF + t * 32 + grp * 8];
        const float4 xb = *(const float4*)&x[(size_t)rc * NF + t * 32 + grp * 8 + 4];
        union { bfrag v; unsigned int u[4]; } pk;
        pk.u[0] = (unsigned int)f2bf(xa.x) | ((unsigned int)f2bf(xa.y) << 16);
        pk.u[1] = (unsigned int)f2bf(xa.z) | ((unsigned int)f2bf(xa.w) << 16);
        pk.u[2] = (unsigned int)f2bf(xb.x) | ((unsigned int)f2bf(xb.y) << 16);
        pk.u[3] = (unsigned int)f2bf(xb.z) | ((unsigned int)f2bf(xb.w) << 16);
        bx[t] = pk.v;
    }

    const bfrag* w1f = (const bfrag*)wfrag;                 // [(ci*2+t)*64 + lane]
    const bfrag* w2f = (const bfrag*)(wfrag + 4096);        // [(ci*4+t)*64 + lane]
    float fp = 0.f;

    // ---- GEMM1: C1[channel][row], 8 channel-tiles x K=64 ----
    #pragma unroll
    for (int ci = 0; ci < 8; ++ci) {
        f32x4 c1 = {0.f, 0.f, 0.f, 0.f};
        c1 = __builtin_amdgcn_mfma_f32_16x16x32_bf16(w1f[(ci * 2 + 0) * 64 + lane], bx[0], c1, 0, 0, 0);
        c1 = __builtin_amdgcn_mfma_f32_16x16x32_bf16(w1f[(ci * 2 + 1) * 64 + lane], bx[1], c1, 0, 0, 0);
        const int c0 = ci * 16 + grp * 4;                   // channel base (4 contiguous)
        const float4 b1v = *(const float4*)&b1[c0];
        const float4 wfa = *(const float4*)&Wfc[2 * c0];        // we(c0),wo(c0),we(c0+1),wo(c0+1)
        const float4 wfb = *(const float4*)&Wfc[2 * c0 + 4];
        const float h0 = fmaxf(c1[0] + b1v.x, 0.f);
        const float h1 = fmaxf(c1[1] + b1v.y, 0.f);
        const float h2 = fmaxf(c1[2] + b1v.z, 0.f);
        const float h3 = fmaxf(c1[3] + b1v.w, 0.f);
        fp = fmaf(h0, wfa.x, fp); fp = fmaf(h1, wfa.z, fp);
        fp = fmaf(h2, wfb.x, fp); fp = fmaf(h3, wfb.z, fp);
        const unsigned int lo = (unsigned int)f2bf(h0) | ((unsigned int)f2bf(h1) << 16);
        const unsigned int hi = (unsigned int)f2bf(h2) | ((unsigned int)f2bf(h3) << 16);
        *(uint2*)&h1s[wid][sub][c0] = make_uint2(lo, hi);   // wave-private stash
    }

    // ---- GEMM2: B = h1^T from stash (b128, bank-balanced), K=128 ----
    bfrag bh[4];
    #pragma unroll
    for (int t = 0; t < 4; ++t)
        bh[t] = *(const bfrag*)&h1s[wid][sub][t * 32 + grp * 8];

    #pragma unroll
    for (int ci = 0; ci < 8; ++ci) {
        f32x4 c2 = {0.f, 0.f, 0.f, 0.f};
        #pragma unroll
        for (int t = 0; t < 4; ++t)
            c2 = __builtin_amdgcn_mfma_f32_16x16x32_bf16(w2f[(ci * 4 + t) * 64 + lane], bh[t], c2, 0, 0, 0);
        const int c0 = ci * 16 + grp * 4;
        const float4 b2v = *(const float4*)&b2[c0];
        const float4 wfa = *(const float4*)&Wfc[2 * c0];
        const float4 wfb = *(const float4*)&Wfc[2 * c0 + 4];
        fp = fmaf(fmaxf(c2[0] + b2v.x, 0.f), wfa.y, fp);
        fp = fmaf(fmaxf(c2[1] + b2v.y, 0.f), wfa.w, fp);
        fp = fmaf(fmaxf(c2[2] + b2v.z, 0.f), wfb.y, fp);
        fp = fmaf(fmaxf(c2[3] + b2v.w, 0.f), wfb.w, fp);
    }

    // reduce over channel groups (lane bits 4,5); row = sub
    fp += __shfl_xor(fp, 16);
    fp += __shfl_xor(fp, 32);
    if (grp == 0 && r < MROWS) {
        const int b = r / NG;           // batch
        const int g = r - b * NG;       // gene
        fdot4[g * 4 + b] = fp;          // transposed: one float4 per gene
    }
}

// ---------------------------------------------------------------------------
// K2: privatized edge scatter.  Each block: LDS segment-sum over its edge
// slice (ds_add_f32, no global atomics), then coalesced partial store.
// partial[blk][PSTR]: [b*1000+c] b<4 ; [4000+c] = cnt (as float)
// ---------------------------------------------------------------------------
__global__ __launch_bounds__(256) void k2_scatter(const int* __restrict__ row,
                                                  const int* __restrict__ col,
                                                  const float* __restrict__ fdot4,
                                                  float* __restrict__ partial) {
    __shared__ float lacc[5 * NCMT];    // 20 KB
    const int tid = threadIdx.x;
    #pragma unroll
    for (int i = tid; i < 5 * NCMT; i += 256) lacc[i] = 0.f;
    __syncthreads();

    for (int e = blockIdx.x * 256 + tid; e < NEDGE; e += NB * 256) {
        const int r = row[e];
        const int c = col[e];
        const float4 f = *(const float4*)&fdot4[r * 4];
        atomicAdd(&lacc[c],            f.x);
        atomicAdd(&lacc[NCMT + c],     f.y);
        atomicAdd(&lacc[2 * NCMT + c], f.z);
        atomicAdd(&lacc[3 * NCMT + c], f.w);
        atomicAdd(&lacc[4 * NCMT + c], 1.f);
    }
    __syncthreads();

    float* dst = partial + (size_t)blockIdx.x * PSTR;
    #pragma unroll
    for (int i = tid; i < 5 * NCMT; i += 256) dst[i] = lacc[i];
}

// ---------------------------------------------------------------------------
// K3a: reduce partials -> scores for a 25-col chunk, then
//      hacc[b][j] += sum_{c in chunk} scores[b][c] * Wl1[c][j]
// ---------------------------------------------------------------------------
#define CCH 25
__global__ __launch_bounds__(256) void k3a_head1(const float* __restrict__ partial,
                                                 const float* __restrict__ bfc,
                                                 const float* __restrict__ Wl1,
                                                 float* __restrict__ hacc) {
    __shared__ float tmp[5][CCH];
    __shared__ float sc[BSZ][CCH];
    const int c0 = blockIdx.x * CCH;
    const int t = threadIdx.x;

    if (t < 5 * CCH) {
        const int v = t / CCH, cc = t % CCH;
        float s = 0.f;
        #pragma unroll 8
        for (int blk = 0; blk < NB; ++blk)
            s += partial[(size_t)blk * PSTR + v * NCMT + c0 + cc];
        tmp[v][cc] = s;
    }
    __syncthreads();
    if (t < BSZ * CCH) {
        const int b = t / CCH, cc = t % CCH;
        sc[b][cc] = tmp[b][cc] / fmaxf(tmp[4][cc], 1.f) + bfc[0];
    }
    __syncthreads();

    float p0 = 0.f, p1 = 0.f, p2 = 0.f, p3 = 0.f;
    #pragma unroll
    for (int cc = 0; cc < CCH; ++cc) {
        const float wv = Wl1[(size_t)(c0 + cc) * HFC + t];
        p0 = fmaf(sc[0][cc], wv, p0);
        p1 = fmaf(sc[1][cc], wv, p1);
        p2 = fmaf(sc[2][cc], wv, p2);
        p3 = fmaf(sc[3][cc], wv, p3);
    }
    atomicAdd(&hacc[0 * HFC + t], p0);
    atomicAdd(&hacc[1 * HFC + t], p1);
    atomicAdd(&hacc[2 * HFC + t], p2);
    atomicAdd(&hacc[3 * HFC + t], p3);
}

// ---------------------------------------------------------------------------
// K3b: logits = relu(hacc) @ Wl2 + bl2 ; out = log_softmax(logits)
// ---------------------------------------------------------------------------
__global__ __launch_bounds__(64) void k3b_head2(const float* __restrict__ hacc,
                                                const float* __restrict__ Wl2,
                                                const float* __restrict__ bl2,
                                                float* __restrict__ out) {
    __shared__ float lg[BSZ][NCLS];
    const int t = threadIdx.x;
    if (t < BSZ * NCLS) {
        const int b = t / NCLS, k = t % NCLS;
        float a = bl2[k];
        for (int j = 0; j < HFC; ++j)
            a = fmaf(fmaxf(hacc[b * HFC + j], 0.f), Wl2[j * NCLS + k], a);
        lg[b][k] = a;
    }
    __syncthreads();
    if (t < BSZ * NCLS) {
        const int b = t / NCLS, k = t % NCLS;
        float m = lg[b][0];
        #pragma unroll
        for (int k2 = 1; k2 < NCLS; ++k2) m = fmaxf(m, lg[b][k2]);
        float s = 0.f;
        #pragma unroll
        for (int k2 = 0; k2 < NCLS; ++k2) s += expf(lg[b][k2] - m);
        out[b * NCLS + k] = lg[b][k] - m - logf(s);
    }
}

// ---------------------------------------------------------------------------
extern "C" void kernel_launch(void* const* d_in, const int* in_sizes, int n_in,
                              void* d_out, int out_size, void* d_ws, size_t ws_size,
                              hipStream_t stream) {
    const float* x   = (const float*)d_in[0];
    // d_in[1] = batch (unused)
    const int*   row = (const int*)d_in[2];
    const int*   col = (const int*)d_in[3];
    const float* W1  = (const float*)d_in[4];
    const float* b1  = (const float*)d_in[5];
    const float* W2  = (const float*)d_in[6];
    const float* b2  = (const float*)d_in[7];
    const float* Wfc = (const float*)d_in[8];
    const float* bfc = (const float*)d_in[9];
    const float* Wl1 = (const float*)d_in[10];
    const float* bl1 = (const float*)d_in[11];
    const float* Wl2 = (const float*)d_in[12];
    const float* bl2 = (const float*)d_in[13];

    float* ws      = (float*)d_ws;
    float* fdot4   = ws;                                   // 242,160 floats (NG*4 rounded)
    float* partial = ws + 242176;                          // NB*PSTR = 327,680 floats
    float* hacc    = partial + (size_t)NB * PSTR;          // 1024
    unsigned int* wfrag = (unsigned int*)(hacc + 1024);    // 12,288 u32

    kP<<<48, 256, 0, stream>>>(W1, W2, bl1, wfrag, hacc);
    k1_fdot<<<(MROWS + 63) / 64, 256, 0, stream>>>(x, wfrag, b1, b2, Wfc, fdot4);
    k2_scatter<<<NB, 256, 0, stream>>>(row, col, fdot4, partial);
    k3a_head1<<<NCMT / CCH, 256, 0, stream>>>(partial, bfc, Wl1, hacc);
    k3b_head2<<<1, 64, 0, stream>>>(hacc, Wl2, bl2, (float*)d_out);
}